// Round 9
// baseline (398.854 us; speedup 1.0000x reference)
//
#include <hip/hip_runtime.h>
#include <hip/hip_bf16.h>

typedef __attribute__((ext_vector_type(8))) short s16x8;
typedef __attribute__((ext_vector_type(4))) float f32x4;
typedef __attribute__((ext_vector_type(2))) float f32x2;

__device__ inline unsigned int f2bf(float f) {
    union { float f; unsigned int i; } v;
    v.f = f;
    return (v.i + 0x7FFFu + ((v.i >> 16) & 1u)) >> 16;   // RNE
}
__device__ inline unsigned char f2fp8(float v) {
    const int p = __builtin_amdgcn_cvt_pk_fp8_f32(v, v, 0, false);
    return (unsigned char)(p & 0xFF);
}

// ---------- prep: weight transposes (bf16) + bias concat ----------
__global__ __launch_bounds__(256) void prep_w(
    const float* __restrict__ Wq, const float* __restrict__ Wk,
    const float* __restrict__ W1, const float* __restrict__ W2,
    const float* __restrict__ Wp,
    const float* __restrict__ bq, const float* __restrict__ bk,
    const float* __restrict__ b1,
    unsigned short* __restrict__ Wtqkt, unsigned short* __restrict__ Wt2,
    unsigned short* __restrict__ Wtp, float* __restrict__ bqkt)
{
    const int tid = threadIdx.x;
    int b = blockIdx.x;
    if (b < 1024) {                          // 4 x 256x256 weights
        const int w = b >> 8;
        const int i = (b & 255) * 256 + tid;
        const int k = i >> 8, j = i & 255;   // coalesced read of W[k][j]
        const float* W = (w == 0) ? Wq : (w == 1) ? Wk : (w == 2) ? W1 : W2;
        unsigned short* dst = (w == 3) ? Wt2 : (Wtqkt + w * 65536);
        dst[j * 256 + k] = (unsigned short)f2bf(W[i]);
        return;
    }
    b -= 1024;
    if (b < 512) {                           // Wpred [256][512] -> Wtp [512][256]
        const int i = b * 256 + tid;
        const int k = i >> 9, j = i & 511;
        Wtp[(size_t)j * 256 + k] = (unsigned short)f2bf(Wp[i]);
        return;
    }
    b -= 512;
    {                                        // bqkt = [bq | bk | b1]
        const int i = b * 256 + tid;
        bqkt[i] = (i < 256) ? bq[i] : (i < 512) ? bk[i - 256] : b1[i - 512];
    }
}

// ---------- generic MFMA GEMM job ----------
struct GemmJob {
    const void* A;                 // [M][256], f32 (a_f32=1) or bf16
    const unsigned short* Wt;      // [Nout][256] bf16
    const float* bias;             // [Nout] or nullptr
    void* out1;                    // cols [0, split)
    void* out2;                    // cols [split, Nout)
    int Nout;
    int split;
    int relu_lo, relu_hi;          // relu for cols in [relu_lo, relu_hi)
    int a_f32;
    int fp8_1, fp8_2;              // out1/out2 stored as fp8 e4m3 (else bf16)
};

__device__ inline void job_store(const GemmJob& J, int row, int col, float v, int M) {
    if (row >= M) return;
    if (J.bias) v += J.bias[col];
    if (col >= J.relu_lo && col < J.relu_hi) v = fmaxf(v, 0.0f);
    const bool lo = (col < J.split);
    void* o = lo ? J.out1 : J.out2;
    const int stride = lo ? J.split : (J.Nout - J.split);
    const int cc = lo ? col : col - J.split;
    const int f8 = lo ? J.fp8_1 : J.fp8_2;
    if (f8) ((unsigned char*)o)[(size_t)row * stride + cc] = f2fp8(v);
    else    ((unsigned short*)o)[(size_t)row * stride + cc] = (unsigned short)f2bf(v);
}

// Block: 64 rows, 4 waves (2x2), per-wave 32x32 C via 2x2 16x16x32 bf16 frags.
// A tile + B chunk LDS-resident, XOR-swizzled (G4). blockIdx.y selects the job.
__global__ __launch_bounds__(256) void gemm_multi(
    GemmJob j0, GemmJob j1, int M)
{
    __shared__ __align__(16) char smem[65536];
    char* ldsA = smem;
    char* ldsB = smem + 32768;
    const GemmJob J = (blockIdx.y == 0) ? j0 : j1;

    const int tid  = threadIdx.x;
    const int wid  = tid >> 6, lane = tid & 63;
    const int wr   = wid >> 1, wc = wid & 1;
    const int r0   = blockIdx.x * 64;
    const int swz  = (lane & 7) << 4;

    if (J.a_f32) {
        const float* Af = (const float*)J.A;
        for (int i = tid; i < 2048; i += 256) {
            const int row = i >> 5, off = i & 31;
            const int gr = r0 + row;
            uint4 v = make_uint4(0, 0, 0, 0);
            if (gr < M) {
                const float4 a = *(const float4*)(Af + (size_t)gr * 256 + off * 8);
                const float4 c = *(const float4*)(Af + (size_t)gr * 256 + off * 8 + 4);
                v.x = f2bf(a.x) | (f2bf(a.y) << 16);
                v.y = f2bf(a.z) | (f2bf(a.w) << 16);
                v.z = f2bf(c.x) | (f2bf(c.y) << 16);
                v.w = f2bf(c.z) | (f2bf(c.w) << 16);
            }
            const int b = (row * 512 + off * 16) ^ ((row & 7) << 4);
            *(uint4*)(ldsA + b) = v;
        }
    } else {
        const unsigned short* Ab = (const unsigned short*)J.A;
        for (int i = tid; i < 2048; i += 256) {
            const int row = i >> 5, off = i & 31;
            const int gr = r0 + row;
            uint4 v = make_uint4(0, 0, 0, 0);
            if (gr < M) v = *(const uint4*)(Ab + (size_t)gr * 256 + off * 8);
            const int b = (row * 512 + off * 16) ^ ((row & 7) << 4);
            *(uint4*)(ldsA + b) = v;
        }
    }

    const int ro = lane & 15, ko = (lane >> 4) * 16;
    const int baseA0 = (wr * 32 +  0 + ro) * 512 + ko;
    const int baseA1 = (wr * 32 + 16 + ro) * 512 + ko;
    const int baseB0 = (wc * 32 +  0 + ro) * 512 + ko;
    const int baseB1 = (wc * 32 + 16 + ro) * 512 + ko;

    const int nchunks = J.Nout >> 6;
    for (int c = 0; c < nchunks; ++c) {
        const int j0c = c << 6;
        for (int i = tid; i < 2048; i += 256) {
            const int row = i >> 5, off = i & 31;
            const uint4 v = *(const uint4*)(J.Wt + (size_t)(j0c + row) * 256 + off * 8);
            const int b = (row * 512 + off * 16) ^ ((row & 7) << 4);
            *(uint4*)(ldsB + b) = v;
        }
        __syncthreads();

        f32x4 acc00 = {0,0,0,0}, acc01 = {0,0,0,0}, acc10 = {0,0,0,0}, acc11 = {0,0,0,0};
#pragma unroll
        for (int kk = 0; kk < 8; ++kk) {
            const int kb = kk * 64;
            const s16x8 a0 = *(const s16x8*)(ldsA + ((baseA0 + kb) ^ swz));
            const s16x8 a1 = *(const s16x8*)(ldsA + ((baseA1 + kb) ^ swz));
            const s16x8 b0 = *(const s16x8*)(ldsB + ((baseB0 + kb) ^ swz));
            const s16x8 b1 = *(const s16x8*)(ldsB + ((baseB1 + kb) ^ swz));
            acc00 = __builtin_amdgcn_mfma_f32_16x16x32_bf16(a0, b0, acc00, 0, 0, 0);
            acc01 = __builtin_amdgcn_mfma_f32_16x16x32_bf16(a0, b1, acc01, 0, 0, 0);
            acc10 = __builtin_amdgcn_mfma_f32_16x16x32_bf16(a1, b0, acc10, 0, 0, 0);
            acc11 = __builtin_amdgcn_mfma_f32_16x16x32_bf16(a1, b1, acc11, 0, 0, 0);
        }

        const int colb = j0c + wc * 32;
        const int rb0 = r0 + wr * 32 + (lane >> 4) * 4;
        const int rb1 = rb0 + 16;
#pragma unroll
        for (int r = 0; r < 4; ++r) {
            job_store(J, rb0 + r, colb + ro,      acc00[r], M);
            job_store(J, rb0 + r, colb + 16 + ro, acc01[r], M);
            job_store(J, rb1 + r, colb + ro,      acc10[r], M);
            job_store(J, rb1 + r, colb + 16 + ro, acc11[r], M);
        }
        __syncthreads();
    }
}

// ---------- edge kernel v2: 64 edges per wave, depth-2 gather pipeline ----------
// Phase 0: coalesced index loads for 64 edges (one per lane). Main loop:
// while computing edge j (whole wave), edge j+1's 4 gathers are in flight.
__global__ __launch_bounds__(256) void edge_fused_v2(
    const unsigned char* __restrict__ qkb,
    const unsigned char* __restrict__ hp, const unsigned char* __restrict__ gp,
    const float* __restrict__ bpred,
    const int* __restrict__ edge_src, const int* __restrict__ node_ids,
    const int* __restrict__ masked_idx, const int* __restrict__ edge_idx,
    float* __restrict__ out, int P)
{
    const int wid  = threadIdx.x >> 6, lane = threadIdx.x & 63;
    const int ebase = (blockIdx.x * 4 + wid) * 64;
    if (ebase >= P) return;
    const int ne = min(64, P - ebase);

    // phase 0: per-lane indices for this wave's 64 edges (coalesced)
    int mi = 0, c = 0, s = 0;
    if (lane < ne) {
        mi = masked_idx[ebase + lane];
        c  = node_ids[mi];
        s  = edge_src[edge_idx[ebase + lane]];
    }
    if (lane < ne) out[(size_t)P * 512 + ebase + lane] = (float)mi;   // output 1, coalesced

    const float4 bp0 = *(const float4*)&bpred[lane * 8];
    const float4 bp1 = *(const float4*)&bpred[lane * 8 + 4];

    auto issue = [&](int j, unsigned int& qw, unsigned int& kw, uint2& hv, uint2& gv) {
        const int cj = __shfl(c, j, 64);
        const int sj = __shfl(s, j, 64);
        qw = *(const unsigned int*)(qkb + (size_t)cj * 512 + lane * 4);
        kw = *(const unsigned int*)(qkb + (size_t)sj * 512 + 256 + lane * 4);
        hv = *(const uint2*)(hp + (size_t)cj * 512 + lane * 8);
        gv = *(const uint2*)(gp + (size_t)sj * 512 + lane * 8);
    };
    auto do_edge = [&](int j, unsigned int qw, unsigned int kw, uint2 hv, uint2 gv) {
        const f32x2 q01 = __builtin_amdgcn_cvt_pk_f32_fp8(qw, false);
        const f32x2 q23 = __builtin_amdgcn_cvt_pk_f32_fp8(qw, true);
        const f32x2 k01 = __builtin_amdgcn_cvt_pk_f32_fp8(kw, false);
        const f32x2 k23 = __builtin_amdgcn_cvt_pk_f32_fp8(kw, true);
        float dot = q01.x * k01.x + q01.y * k01.y + q23.x * k23.x + q23.y * k23.y;
#pragma unroll
        for (int off = 32; off; off >>= 1) dot += __shfl_xor(dot, off, 64);
        const float a = 1.0f / (1.0f + expf(-dot));
        const float oma = 1.0f - a;

        const f32x2 h0 = __builtin_amdgcn_cvt_pk_f32_fp8(hv.x, false);
        const f32x2 h1 = __builtin_amdgcn_cvt_pk_f32_fp8(hv.x, true);
        const f32x2 h2 = __builtin_amdgcn_cvt_pk_f32_fp8(hv.y, false);
        const f32x2 h3 = __builtin_amdgcn_cvt_pk_f32_fp8(hv.y, true);
        const f32x2 g0 = __builtin_amdgcn_cvt_pk_f32_fp8(gv.x, false);
        const f32x2 g1 = __builtin_amdgcn_cvt_pk_f32_fp8(gv.x, true);
        const f32x2 g2 = __builtin_amdgcn_cvt_pk_f32_fp8(gv.y, false);
        const f32x2 g3 = __builtin_amdgcn_cvt_pk_f32_fp8(gv.y, true);

        f32x4 r0, r1;
        r0[0] = fmaf(a, h0.x, fmaf(oma, g0.x, bp0.x));
        r0[1] = fmaf(a, h0.y, fmaf(oma, g0.y, bp0.y));
        r0[2] = fmaf(a, h1.x, fmaf(oma, g1.x, bp0.z));
        r0[3] = fmaf(a, h1.y, fmaf(oma, g1.y, bp0.w));
        r1[0] = fmaf(a, h2.x, fmaf(oma, g2.x, bp1.x));
        r1[1] = fmaf(a, h2.y, fmaf(oma, g2.y, bp1.y));
        r1[2] = fmaf(a, h3.x, fmaf(oma, g3.x, bp1.z));
        r1[3] = fmaf(a, h3.y, fmaf(oma, g3.y, bp1.w));

        float* dst = &out[(size_t)(ebase + j) * 512 + lane * 8];
        __builtin_nontemporal_store(r0, (f32x4*)dst);
        __builtin_nontemporal_store(r1, (f32x4*)(dst + 4));
    };

    unsigned int qA, kA; uint2 hA, gA;
    unsigned int qB, kB; uint2 hB, gB;

    if (ne == 64) {
        issue(0, qA, kA, hA, gA);
        for (int j = 0; j < 64; j += 2) {
            issue(j + 1, qB, kB, hB, gB);        // j+1 <= 63
            do_edge(j, qA, kA, hA, gA);
            if (j + 2 < 64) issue(j + 2, qA, kA, hA, gA);
            do_edge(j + 1, qB, kB, hB, gB);
        }
    } else {
        for (int j = 0; j < ne; ++j) {
            issue(j, qA, kA, hA, gA);
            do_edge(j, qA, kA, hA, gA);
        }
    }
}

extern "C" void kernel_launch(void* const* d_in, const int* in_sizes, int n_in,
                              void* d_out, int out_size, void* d_ws, size_t ws_size,
                              hipStream_t stream) {
    const float* h_mask = (const float*)d_in[0];
    const float* z      = (const float*)d_in[1];
    const float* Wq     = (const float*)d_in[2];
    const float* bq     = (const float*)d_in[3];
    const float* Wk     = (const float*)d_in[4];
    const float* bk     = (const float*)d_in[5];
    const float* W1     = (const float*)d_in[6];
    const float* b1     = (const float*)d_in[7];
    const float* W2     = (const float*)d_in[8];
    const float* b2     = (const float*)d_in[9];
    const float* Wpred  = (const float*)d_in[10];
    const float* bpred  = (const float*)d_in[11];
    const int* edge_index = (const int*)d_in[12];
    const int* node_ids   = (const int*)d_in[13];
    const int* masked_idx = (const int*)d_in[14];
    const int* edge_idx   = (const int*)d_in[15];

    const int N = in_sizes[13];
    const int P = in_sizes[14];

    // ---- workspace layout ----
    unsigned char*  qkb   = (unsigned char*)d_ws;                  // [N][512] fp8 = q|k
    unsigned char*  gpb   = qkb + (size_t)N * 512;                 // [N][512] fp8
    unsigned char*  hpb   = gpb + (size_t)N * 512;                 // [N][512] fp8
    unsigned short* tb    = (unsigned short*)(hpb + (size_t)N * 512);  // [N][256] bf16
    unsigned short* gb    = tb  + (size_t)N * 256;                 // [N][256] bf16
    unsigned short* Wtqkt = gb  + (size_t)N * 256;                 // [768][256] bf16
    unsigned short* Wt2   = Wtqkt + 196608;                        // [256][256]
    unsigned short* Wtp   = Wt2   + 65536;                         // [512][256]
    float*          bqkt  = (float*)(Wtp + 131072);                // [768]

    const dim3 blk(256);
    const int gb64 = (N + 63) / 64;
    const int eb2  = (P + 255) / 256;

    // 1. weights-only prep
    prep_w<<<dim3(1024 + 512 + 3), blk, 0, stream>>>(
        Wq, Wk, W1, W2, Wpred, bq, bk, b1, Wtqkt, Wt2, Wtp, bqkt);

    // 2. jobA0: [q|k (fp8) | t (bf16)] = act(z @ [Wq|Wk|W1] + [bq|bk|b1])
    //    jobA1: hp (fp8) = h_mask @ Wpred
    GemmJob a0 = { z,      Wtqkt, bqkt,    qkb, tb,      768, 512, 512, 768, 1, 1, 0 };
    GemmJob a1 = { h_mask, Wtp,   nullptr, hpb, nullptr, 512, 512, 0,   0,   1, 1, 0 };
    gemm_multi<<<dim3(gb64, 2), blk, 0, stream>>>(a0, a1, N);

    // 3. g (bf16) = t @ W2 + b2
    GemmJob b0 = { tb, Wt2, b2, gb, nullptr, 256, 256, 0, 0, 0, 0, 0 };
    gemm_multi<<<dim3(gb64, 1), blk, 0, stream>>>(b0, b0, N);

    // 4. gp (fp8) = g @ Wpred
    GemmJob c0 = { gb, Wtp, nullptr, gpb, nullptr, 512, 512, 0, 0, 0, 1, 0 };
    gemm_multi<<<dim3(gb64, 1), blk, 0, stream>>>(c0, c0, N);

    // 5. edge phase v2 (64 edges/wave, pipelined gathers, nt stores)
    edge_fused_v2<<<dim3(eb2), blk, 0, stream>>>(qkb, hpb, gpb, bpred,
                                                 edge_index, node_ids, masked_idx, edge_idx,
                                                 (float*)d_out, P);
}

// Round 10
// 319.922 us; speedup vs baseline: 1.2467x; 1.2467x over previous
//
#include <hip/hip_runtime.h>
#include <hip/hip_bf16.h>

typedef __attribute__((ext_vector_type(8))) short s16x8;
typedef __attribute__((ext_vector_type(4))) float f32x4;
typedef __attribute__((ext_vector_type(2))) float f32x2;

__device__ inline unsigned int f2bf(float f) {
    union { float f; unsigned int i; } v;
    v.f = f;
    return (v.i + 0x7FFFu + ((v.i >> 16) & 1u)) >> 16;   // RNE
}
__device__ inline unsigned char f2fp8(float v) {
    const int p = __builtin_amdgcn_cvt_pk_fp8_f32(v, v, 0, false);
    return (unsigned char)(p & 0xFF);
}

// ---------- prep: weight transposes (bf16) + bias concat ----------
__global__ __launch_bounds__(256) void prep_w(
    const float* __restrict__ Wq, const float* __restrict__ Wk,
    const float* __restrict__ W1, const float* __restrict__ W2,
    const float* __restrict__ Wp,
    const float* __restrict__ bq, const float* __restrict__ bk,
    const float* __restrict__ b1,
    unsigned short* __restrict__ Wtqkt, unsigned short* __restrict__ Wt2,
    unsigned short* __restrict__ Wtp, float* __restrict__ bqkt)
{
    const int tid = threadIdx.x;
    int b = blockIdx.x;
    if (b < 1024) {                          // 4 x 256x256 weights
        const int w = b >> 8;
        const int i = (b & 255) * 256 + tid;
        const int k = i >> 8, j = i & 255;   // coalesced read of W[k][j]
        const float* W = (w == 0) ? Wq : (w == 1) ? Wk : (w == 2) ? W1 : W2;
        unsigned short* dst = (w == 3) ? Wt2 : (Wtqkt + w * 65536);
        dst[j * 256 + k] = (unsigned short)f2bf(W[i]);
        return;
    }
    b -= 1024;
    if (b < 512) {                           // Wpred [256][512] -> Wtp [512][256]
        const int i = b * 256 + tid;
        const int k = i >> 9, j = i & 511;
        Wtp[(size_t)j * 256 + k] = (unsigned short)f2bf(Wp[i]);
        return;
    }
    b -= 512;
    {                                        // bqkt = [bq | bk | b1]
        const int i = b * 256 + tid;
        bqkt[i] = (i < 256) ? bq[i] : (i < 512) ? bk[i - 256] : b1[i - 512];
    }
}

// ---------- generic MFMA GEMM job ----------
struct GemmJob {
    const void* A;                 // [M][256], f32 (a_f32=1) or bf16
    const unsigned short* Wt;      // [Nout][256] bf16
    const float* bias;             // [Nout] or nullptr
    void* out1;                    // cols [0, split)
    void* out2;                    // cols [split, Nout)
    int Nout;
    int split;
    int relu_lo, relu_hi;          // relu for cols in [relu_lo, relu_hi)
    int a_f32;
    int fp8_1, fp8_2;              // out1/out2 stored as fp8 e4m3 (else bf16)
};

__device__ inline void job_store(const GemmJob& J, int row, int col, float v, int M) {
    if (row >= M) return;
    if (J.bias) v += J.bias[col];
    if (col >= J.relu_lo && col < J.relu_hi) v = fmaxf(v, 0.0f);
    const bool lo = (col < J.split);
    void* o = lo ? J.out1 : J.out2;
    const int stride = lo ? J.split : (J.Nout - J.split);
    const int cc = lo ? col : col - J.split;
    const int f8 = lo ? J.fp8_1 : J.fp8_2;
    if (f8) ((unsigned char*)o)[(size_t)row * stride + cc] = f2fp8(v);
    else    ((unsigned short*)o)[(size_t)row * stride + cc] = (unsigned short)f2bf(v);
}

// Block: 64 rows, 4 waves (2x2), per-wave 32x32 C via 2x2 16x16x32 bf16 frags.
// A tile + B chunk LDS-resident, XOR-swizzled (G4). blockIdx.y selects the job.
__global__ __launch_bounds__(256) void gemm_multi(
    GemmJob j0, GemmJob j1, int M)
{
    __shared__ __align__(16) char smem[65536];
    char* ldsA = smem;
    char* ldsB = smem + 32768;
    const GemmJob J = (blockIdx.y == 0) ? j0 : j1;

    const int tid  = threadIdx.x;
    const int wid  = tid >> 6, lane = tid & 63;
    const int wr   = wid >> 1, wc = wid & 1;
    const int r0   = blockIdx.x * 64;
    const int swz  = (lane & 7) << 4;

    if (J.a_f32) {
        const float* Af = (const float*)J.A;
        for (int i = tid; i < 2048; i += 256) {
            const int row = i >> 5, off = i & 31;
            const int gr = r0 + row;
            uint4 v = make_uint4(0, 0, 0, 0);
            if (gr < M) {
                const float4 a = *(const float4*)(Af + (size_t)gr * 256 + off * 8);
                const float4 c = *(const float4*)(Af + (size_t)gr * 256 + off * 8 + 4);
                v.x = f2bf(a.x) | (f2bf(a.y) << 16);
                v.y = f2bf(a.z) | (f2bf(a.w) << 16);
                v.z = f2bf(c.x) | (f2bf(c.y) << 16);
                v.w = f2bf(c.z) | (f2bf(c.w) << 16);
            }
            const int b = (row * 512 + off * 16) ^ ((row & 7) << 4);
            *(uint4*)(ldsA + b) = v;
        }
    } else {
        const unsigned short* Ab = (const unsigned short*)J.A;
        for (int i = tid; i < 2048; i += 256) {
            const int row = i >> 5, off = i & 31;
            const int gr = r0 + row;
            uint4 v = make_uint4(0, 0, 0, 0);
            if (gr < M) v = *(const uint4*)(Ab + (size_t)gr * 256 + off * 8);
            const int b = (row * 512 + off * 16) ^ ((row & 7) << 4);
            *(uint4*)(ldsA + b) = v;
        }
    }

    const int ro = lane & 15, ko = (lane >> 4) * 16;
    const int baseA0 = (wr * 32 +  0 + ro) * 512 + ko;
    const int baseA1 = (wr * 32 + 16 + ro) * 512 + ko;
    const int baseB0 = (wc * 32 +  0 + ro) * 512 + ko;
    const int baseB1 = (wc * 32 + 16 + ro) * 512 + ko;

    const int nchunks = J.Nout >> 6;
    for (int c = 0; c < nchunks; ++c) {
        const int j0c = c << 6;
        for (int i = tid; i < 2048; i += 256) {
            const int row = i >> 5, off = i & 31;
            const uint4 v = *(const uint4*)(J.Wt + (size_t)(j0c + row) * 256 + off * 8);
            const int b = (row * 512 + off * 16) ^ ((row & 7) << 4);
            *(uint4*)(ldsB + b) = v;
        }
        __syncthreads();

        f32x4 acc00 = {0,0,0,0}, acc01 = {0,0,0,0}, acc10 = {0,0,0,0}, acc11 = {0,0,0,0};
#pragma unroll
        for (int kk = 0; kk < 8; ++kk) {
            const int kb = kk * 64;
            const s16x8 a0 = *(const s16x8*)(ldsA + ((baseA0 + kb) ^ swz));
            const s16x8 a1 = *(const s16x8*)(ldsA + ((baseA1 + kb) ^ swz));
            const s16x8 b0 = *(const s16x8*)(ldsB + ((baseB0 + kb) ^ swz));
            const s16x8 b1 = *(const s16x8*)(ldsB + ((baseB1 + kb) ^ swz));
            acc00 = __builtin_amdgcn_mfma_f32_16x16x32_bf16(a0, b0, acc00, 0, 0, 0);
            acc01 = __builtin_amdgcn_mfma_f32_16x16x32_bf16(a0, b1, acc01, 0, 0, 0);
            acc10 = __builtin_amdgcn_mfma_f32_16x16x32_bf16(a1, b0, acc10, 0, 0, 0);
            acc11 = __builtin_amdgcn_mfma_f32_16x16x32_bf16(a1, b1, acc11, 0, 0, 0);
        }

        const int colb = j0c + wc * 32;
        const int rb0 = r0 + wr * 32 + (lane >> 4) * 4;
        const int rb1 = rb0 + 16;
#pragma unroll
        for (int r = 0; r < 4; ++r) {
            job_store(J, rb0 + r, colb + ro,      acc00[r], M);
            job_store(J, rb0 + r, colb + 16 + ro, acc01[r], M);
            job_store(J, rb1 + r, colb + ro,      acc10[r], M);
            job_store(J, rb1 + r, colb + 16 + ro, acc11[r], M);
        }
        __syncthreads();
    }
}

// ---------- fused edge kernel (R7 structure + nontemporal stores) ----------
// qkb rows: [q(256B) | k(256B)] fp8; hp/gp rows: 512B fp8. One wave per edge.
__global__ __launch_bounds__(256) void edge_fused(
    const unsigned char* __restrict__ qkb,
    const unsigned char* __restrict__ hp, const unsigned char* __restrict__ gp,
    const float* __restrict__ bpred,
    const int* __restrict__ edge_src, const int* __restrict__ node_ids,
    const int* __restrict__ masked_idx, const int* __restrict__ edge_idx,
    float* __restrict__ out, int P)
{
    const int wave = threadIdx.x >> 6;
    const int lane = threadIdx.x & 63;
    const int e = blockIdx.x * 4 + wave;
    if (e >= P) return;

    const int mi = masked_idx[e];
    const int c  = node_ids[mi];
    const int s  = edge_src[edge_idx[e]];

    // dot(q[c], k[s]) — 4 fp8 elems/lane each
    const unsigned int qw = *(const unsigned int*)(qkb + (size_t)c * 512 + lane * 4);
    const unsigned int kw = *(const unsigned int*)(qkb + (size_t)s * 512 + 256 + lane * 4);
    const f32x2 q01 = __builtin_amdgcn_cvt_pk_f32_fp8(qw, false);
    const f32x2 q23 = __builtin_amdgcn_cvt_pk_f32_fp8(qw, true);
    const f32x2 k01 = __builtin_amdgcn_cvt_pk_f32_fp8(kw, false);
    const f32x2 k23 = __builtin_amdgcn_cvt_pk_f32_fp8(kw, true);
    float dot = q01.x * k01.x + q01.y * k01.y + q23.x * k23.x + q23.y * k23.y;
#pragma unroll
    for (int off = 32; off; off >>= 1) dot += __shfl_xor(dot, off, 64);

    const float a = 1.0f / (1.0f + expf(-dot));
    const float oma = 1.0f - a;

    // 8 outputs/lane
    const uint2 hv = *(const uint2*)(hp + (size_t)c * 512 + lane * 8);
    const uint2 gv = *(const uint2*)(gp + (size_t)s * 512 + lane * 8);
    const float4 bp0 = *(const float4*)&bpred[lane * 8];
    const float4 bp1 = *(const float4*)&bpred[lane * 8 + 4];

    const f32x2 h0 = __builtin_amdgcn_cvt_pk_f32_fp8(hv.x, false);
    const f32x2 h1 = __builtin_amdgcn_cvt_pk_f32_fp8(hv.x, true);
    const f32x2 h2 = __builtin_amdgcn_cvt_pk_f32_fp8(hv.y, false);
    const f32x2 h3 = __builtin_amdgcn_cvt_pk_f32_fp8(hv.y, true);
    const f32x2 g0 = __builtin_amdgcn_cvt_pk_f32_fp8(gv.x, false);
    const f32x2 g1 = __builtin_amdgcn_cvt_pk_f32_fp8(gv.x, true);
    const f32x2 g2 = __builtin_amdgcn_cvt_pk_f32_fp8(gv.y, false);
    const f32x2 g3 = __builtin_amdgcn_cvt_pk_f32_fp8(gv.y, true);

    f32x4 r0, r1;
    r0[0] = fmaf(a, h0.x, fmaf(oma, g0.x, bp0.x));
    r0[1] = fmaf(a, h0.y, fmaf(oma, g0.y, bp0.y));
    r0[2] = fmaf(a, h1.x, fmaf(oma, g1.x, bp0.z));
    r0[3] = fmaf(a, h1.y, fmaf(oma, g1.y, bp0.w));
    r1[0] = fmaf(a, h2.x, fmaf(oma, g2.x, bp1.x));
    r1[1] = fmaf(a, h2.y, fmaf(oma, g2.y, bp1.y));
    r1[2] = fmaf(a, h3.x, fmaf(oma, g3.x, bp1.z));
    r1[3] = fmaf(a, h3.y, fmaf(oma, g3.y, bp1.w));

    float* dst = &out[(size_t)e * 512 + lane * 8];
    __builtin_nontemporal_store(r0, (f32x4*)dst);
    __builtin_nontemporal_store(r1, (f32x4*)(dst + 4));

    // output 1: masked_idx as f32 (nt store too)
    if (lane == 0) {
        __builtin_nontemporal_store((float)mi, &out[(size_t)P * 512 + e]);
    }
}

extern "C" void kernel_launch(void* const* d_in, const int* in_sizes, int n_in,
                              void* d_out, int out_size, void* d_ws, size_t ws_size,
                              hipStream_t stream) {
    const float* h_mask = (const float*)d_in[0];
    const float* z      = (const float*)d_in[1];
    const float* Wq     = (const float*)d_in[2];
    const float* bq     = (const float*)d_in[3];
    const float* Wk     = (const float*)d_in[4];
    const float* bk     = (const float*)d_in[5];
    const float* W1     = (const float*)d_in[6];
    const float* b1     = (const float*)d_in[7];
    const float* W2     = (const float*)d_in[8];
    const float* b2     = (const float*)d_in[9];
    const float* Wpred  = (const float*)d_in[10];
    const float* bpred  = (const float*)d_in[11];
    const int* edge_index = (const int*)d_in[12];
    const int* node_ids   = (const int*)d_in[13];
    const int* masked_idx = (const int*)d_in[14];
    const int* edge_idx   = (const int*)d_in[15];

    const int N = in_sizes[13];
    const int P = in_sizes[14];

    // ---- workspace layout ----
    unsigned char*  qkb   = (unsigned char*)d_ws;                  // [N][512] fp8 = q|k
    unsigned char*  gpb   = qkb + (size_t)N * 512;                 // [N][512] fp8
    unsigned char*  hpb   = gpb + (size_t)N * 512;                 // [N][512] fp8
    unsigned short* tb    = (unsigned short*)(hpb + (size_t)N * 512);  // [N][256] bf16
    unsigned short* gb    = tb  + (size_t)N * 256;                 // [N][256] bf16
    unsigned short* Wtqkt = gb  + (size_t)N * 256;                 // [768][256] bf16
    unsigned short* Wt2   = Wtqkt + 196608;                        // [256][256]
    unsigned short* Wtp   = Wt2   + 65536;                         // [512][256]
    float*          bqkt  = (float*)(Wtp + 131072);                // [768]

    const dim3 blk(256);
    const int gb64 = (N + 63) / 64;
    const int eb   = (P + 3) / 4;

    // 1. weights-only prep
    prep_w<<<dim3(1024 + 512 + 3), blk, 0, stream>>>(
        Wq, Wk, W1, W2, Wpred, bq, bk, b1, Wtqkt, Wt2, Wtp, bqkt);

    // 2. jobA0: [q|k (fp8) | t (bf16)] = act(z @ [Wq|Wk|W1] + [bq|bk|b1])
    //    jobA1: hp (fp8) = h_mask @ Wpred
    GemmJob a0 = { z,      Wtqkt, bqkt,    qkb, tb,      768, 512, 512, 768, 1, 1, 0 };
    GemmJob a1 = { h_mask, Wtp,   nullptr, hpb, nullptr, 512, 512, 0,   0,   1, 1, 0 };
    gemm_multi<<<dim3(gb64, 2), blk, 0, stream>>>(a0, a1, N);

    // 3. g (bf16) = t @ W2 + b2
    GemmJob b0 = { tb, Wt2, b2, gb, nullptr, 256, 256, 0, 0, 0, 0, 0 };
    gemm_multi<<<dim3(gb64, 1), blk, 0, stream>>>(b0, b0, N);

    // 4. gp (fp8) = g @ Wpred
    GemmJob c0 = { gb, Wtp, nullptr, gpb, nullptr, 512, 512, 0, 0, 0, 1, 0 };
    gemm_multi<<<dim3(gb64, 1), blk, 0, stream>>>(c0, c0, N);

    // 5. edge phase (R7 structure, one wave/edge, nt stores)
    edge_fused<<<dim3(eb), blk, 0, stream>>>(qkb, hpb, gpb, bpred,
                                             edge_index, node_ids, masked_idx, edge_idx,
                                             (float*)d_out, P);
}